// Round 2
// baseline (278.370 us; speedup 1.0000x reference)
//
#include <hip/hip_runtime.h>
#include <hip/hip_bf16.h>
#include <math.h>

#define N_TOK 16384
#define DIM   2048
#define NE    64
#define TOPK  9

#define ROWS     64            // rows per block
#define DC       64            // k-elements per chunk
#define NCHUNK   (DIM / DC)    // 32
#define NTHREADS 512           // 8 waves: (rg,cg) = (w>>2, w&3)

typedef short  short8  __attribute__((ext_vector_type(8)));
typedef float  float4_ __attribute__((ext_vector_type(4)));
typedef unsigned short ushort_t;

__device__ __forceinline__ unsigned pk2(float a, float b) {
    float2 f; f.x = a; f.y = b;
    __hip_bfloat162 h = __float22bfloat162_rn(f);   // low16 = bf16(a)
    unsigned u;
    __builtin_memcpy(&u, &h, 4);
    return u;
}

// 8 fp32 -> bf16 hi frag + bf16 lo frag (2-term split)
__device__ __forceinline__ void cvt8(const float4_ va, const float4_ vb,
                                     short8* h, short8* l) {
    union { short8 s; unsigned u[4]; } H, L;
    const float f[8] = {va[0], va[1], va[2], va[3], vb[0], vb[1], vb[2], vb[3]};
#pragma unroll
    for (int i = 0; i < 4; ++i) {
        const float a = f[2 * i], b = f[2 * i + 1];
        const unsigned p = pk2(a, b);
        H.u[i] = p;
        const float ha = __uint_as_float(p << 16);
        const float hb = __uint_as_float(p & 0xffff0000u);
        L.u[i] = pk2(a - ha, b - hb);
    }
    *h = H.s; *l = L.s;
}

__device__ __forceinline__ void wave_max64_2(float& a, float& b) {
#pragma unroll
    for (int off = 32; off > 0; off >>= 1) {
        const float ax = __shfl_xor(a, off, 64);
        const float bx = __shfl_xor(b, off, 64);
        a = fmaxf(a, ax);
        b = fmaxf(b, bx);
    }
}

__device__ __forceinline__ void wave_sum64_3(float& a, float& b, float& c) {
#pragma unroll
    for (int off = 32; off > 0; off >>= 1) {
        const float ax = __shfl_xor(a, off, 64);
        const float bx = __shfl_xor(b, off, 64);
        const float cx = __shfl_xor(c, off, 64);
        a += ax;
        b += bx;
        c += cx;
    }
}

// ---- prep: Wr|Wn (fp32, D x 64 each) -> B-fragment-ordered bf16 hi/lo ----
// slot s=(kcg*8+ct)*2+t holds 512 bf16: elem l*8+j = B[k=kcg*32+(l>>4)*8+j][n=ct*16+(l&15)]
__global__ __launch_bounds__(256)
void prep_w(const float* __restrict__ Wr, const float* __restrict__ Wn,
            ushort_t* __restrict__ wsW)
{
    const int gid = blockIdx.x * 256 + threadIdx.x;   // [0, 64*8*64)
    const int l   = gid & 63;
    const int ct  = (gid >> 6) & 7;
    const int kcg = gid >> 9;                         // 0..63
    const int n   = ct * 16 + (l & 15);
    const int k0  = kcg * 32 + (l >> 4) * 8;
    const float* src = (n < NE) ? (Wr + n) : (Wn + (n - NE));
    union { short8 s; ushort_t us[8]; } H, L;
#pragma unroll
    for (int j = 0; j < 8; ++j) {
        const float v = src[(size_t)(k0 + j) * NE];
        const unsigned uv = __float_as_uint(v);
        const unsigned hb = (uv + 0x7fffu + ((uv >> 16) & 1u)) & 0xffff0000u;
        const float lo = v - __uint_as_float(hb);
        const unsigned ul = __float_as_uint(lo);
        H.us[j] = (ushort_t)(hb >> 16);
        L.us[j] = (ushort_t)((ul + 0x7fffu + ((ul >> 16) & 1u)) >> 16);
    }
    const size_t s0 = (size_t)(kcg * 8 + ct) * 2;     // slot pair index
    *(short8*)(wsW + s0 * 512 + l * 8)         = H.s;
    *(short8*)(wsW + (s0 + 1) * 512 + l * 8)   = L.s;
}

__global__ __launch_bounds__(NTHREADS, 2)
void moe_main(const float* __restrict__ x,
              const float* __restrict__ br,
              const float* __restrict__ bn,
              const float* __restrict__ noise_eps,
              const float* __restrict__ gumbel,
              const ushort_t* __restrict__ wsW,
              float* __restrict__ out)
{
    // LDS only for the epilogue: rawS 64x65 | noiS 64x65 (33.3 KB)
    __shared__ __align__(16) float smem[8320];

    const int t    = threadIdx.x;
    const int lane = t & 63;
    const int w    = t >> 6;          // wave 0..7
    const int c4   = lane & 15;
    const int q    = lane >> 4;
    const int rg   = w >> 2;          // row group 0..1  -> row-tiles {2rg, 2rg+1}
    const int cg   = w & 3;           // col group 0..3  -> col-tiles {2cg, 2cg+1}
    const int row0 = blockIdx.x * ROWS;

    // A fragment pointers: lane l covers A[m = c4][k = q*8 + j] of each 16x32 slab
    const float* pA[2];
#pragma unroll
    for (int rt = 0; rt < 2; ++rt)
        pA[rt] = x + (size_t)(row0 + (2 * rg + rt) * 16 + c4) * DIM + q * 8;

    float4_ acc[2][2];
#pragma unroll
    for (int rt = 0; rt < 2; ++rt)
#pragma unroll
        for (int cc = 0; cc < 2; ++cc)
            acc[rt][cc] = (float4_)(0.f);

    const char* wsB = (const char*)wsW;

    // ---- main loop: pure-register dataflow, no LDS, no barriers ----
#pragma unroll 2
    for (int ch = 0; ch < NCHUNK; ++ch) {
        short8 bh[2][2], bl[2][2];
#pragma unroll
        for (int kc = 0; kc < 2; ++kc)
#pragma unroll
            for (int cc = 0; cc < 2; ++cc) {
                const int ct = 2 * cg + cc;
                const size_t off = (size_t)(((ch * 2 + kc) * 8) + ct) * 2048
                                 + (size_t)lane * 16;
                bh[kc][cc] = *(const short8*)(wsB + off);
                bl[kc][cc] = *(const short8*)(wsB + off + 1024);
            }
#pragma unroll
        for (int kc = 0; kc < 2; ++kc)
#pragma unroll
            for (int rt = 0; rt < 2; ++rt) {
                const float4_ va = *(const float4_*)(pA[rt] + ch * DC + kc * 32);
                const float4_ vb = *(const float4_*)(pA[rt] + ch * DC + kc * 32 + 4);
                short8 ah, al;
                cvt8(va, vb, &ah, &al);
#pragma unroll
                for (int cc = 0; cc < 2; ++cc) {
                    acc[rt][cc] = __builtin_amdgcn_mfma_f32_16x16x32_bf16(ah, bh[kc][cc], acc[rt][cc], 0, 0, 0);
                    acc[rt][cc] = __builtin_amdgcn_mfma_f32_16x16x32_bf16(al, bh[kc][cc], acc[rt][cc], 0, 0, 0);
                    acc[rt][cc] = __builtin_amdgcn_mfma_f32_16x16x32_bf16(ah, bl[kc][cc], acc[rt][cc], 0, 0, 0);
                }
            }
    }

    // ---- epilogue: transpose C tiles through LDS, then per-row wave ops ----
    float* rawS = &smem[0];            // 64 x 65 (padded)
    float* noiS = &smem[4160];         // 64 x 65
#pragma unroll
    for (int rt = 0; rt < 2; ++rt)
#pragma unroll
        for (int cc = 0; cc < 2; ++cc) {
            const int colg = (2 * cg + cc) * 16 + c4;  // 0..127; <64 raw else noise
            float* basep = (colg < NE) ? rawS : noiS;
            const int col = colg & 63;
#pragma unroll
            for (int v = 0; v < 4; ++v) {
                const int row = (2 * rg + rt) * 16 + q * 4 + v;  // C/D: col=lane&15, row=quad*4+reg
                basep[row * 65 + col] = acc[rt][cc][v];
            }
        }
    __syncthreads();

    const float br_l = br[lane];
    const float bn_l = bn[lane];

    // prefetch per-row randomness (8 rows per wave)
    float epsv[8], gumv[8];
#pragma unroll
    for (int r = 0; r < 8; ++r) {
        const int row = row0 + w * 8 + r;
        epsv[r] = noise_eps[(size_t)row * NE + lane];
        gumv[r] = gumbel  [(size_t)row * NE + lane];
    }

    float imp_acc = 0.f, load_acc = 0.f;
    float* out_em   = out;
    float* out_rp   = out + (size_t)N_TOK * NE;
    float* out_imp  = out + (size_t)2 * N_TOK * NE;
    float* out_load = out_imp + NE;

#pragma unroll 1
    for (int r = 0; r < 8; ++r) {
        const int lrow = w * 8 + r;
        const int row  = row0 + lrow;
        const float raw = rawS[lrow * 65 + lane] + br_l;
        const float nl  = noiS[lrow * 65 + lane] + bn_l;
        const float sd = fmaxf(nl, 0.f) + log1pf(expf(-fabsf(nl))) + 0.01f;
        const float noisy = fmaf(epsv[r], sd, raw);

        // ---- threshold = 9th largest via ballot binary search (bit-exact) ----
        const unsigned uk  = __float_as_uint(noisy);
        const unsigned key = uk ^ ((uk & 0x80000000u) ? 0xFFFFFFFFu : 0x80000000u);
        unsigned res = 0;
#pragma unroll
        for (int bit = 31; bit >= 0; --bit) {
            const unsigned cand = res | (1u << bit);
            const int cnt = __popcll(__ballot(key >= cand));
            if (cnt >= TOPK) res = cand;
        }
        const float thr  = __uint_as_float(res ^ ((res & 0x80000000u) ? 0x80000000u : 0xFFFFFFFFu));
        const float hard = (key >= res) ? 1.f : 0.f;

        // fused reductions: one dual-max chain, one triple-sum chain
        const float g = noisy + gumv[r];
        float mg = g, mr = raw;
        wave_max64_2(mg, mr);

        const float eg = expf(g - mg);
        const float en = expf(noisy - thr);   // softmax shift-invariant
        const float er = expf(raw - mr);
        float sg = eg, sn = en, sr = er;
        wave_sum64_3(sg, sn, sr);

        const float ms = eg / sg;
        const float em = (hard - ms) + ms;
        const float rp = en / sn;
        imp_acc += er / sr;

        const float z = (thr - raw) / sd;
        load_acc += 0.5f * erfcf(z * 45.254833995939045f);

        out_em[(size_t)row * NE + lane] = em;
        out_rp[(size_t)row * NE + lane] = rp;
    }

    __syncthreads();                   // rawS/noiS reads done; reuse for reduction
    smem[w * 64 + lane]       = imp_acc;
    smem[512 + w * 64 + lane] = load_acc;
    __syncthreads();
    if (w == 0) {
        float s1 = 0.f, s2 = 0.f;
#pragma unroll
        for (int i = 0; i < 8; ++i) {
            s1 += smem[i * 64 + lane];
            s2 += smem[512 + i * 64 + lane];
        }
        atomicAdd(&out_imp[lane], s1);
        atomicAdd(&out_load[lane], s2);
    }
}

extern "C" void kernel_launch(void* const* d_in, const int* in_sizes, int n_in,
                              void* d_out, int out_size, void* d_ws, size_t ws_size,
                              hipStream_t stream)
{
    const float* x         = (const float*)d_in[0];
    const float* Wr        = (const float*)d_in[1];
    const float* br        = (const float*)d_in[2];
    const float* Wn        = (const float*)d_in[3];
    const float* bn        = (const float*)d_in[4];
    const float* noise_eps = (const float*)d_in[5];
    const float* gumbel    = (const float*)d_in[6];
    float* out = (float*)d_out;
    ushort_t* wsW = (ushort_t*)d_ws;   // 1 MB (64*8*2 slots x 1 KB)

    (void)hipMemsetAsync((char*)d_out + (size_t)2 * N_TOK * NE * sizeof(float), 0,
                         2 * NE * sizeof(float), stream);
    prep_w<<<128, 256, 0, stream>>>(Wr, Wn, wsW);
    moe_main<<<N_TOK / ROWS, NTHREADS, 0, stream>>>(
        x, br, bn, noise_eps, gumbel, wsW, out);
}

// Round 3
// 246.608 us; speedup vs baseline: 1.1288x; 1.1288x over previous
//
#include <hip/hip_runtime.h>
#include <hip/hip_bf16.h>
#include <math.h>

#define N_TOK 16384
#define DIM   2048
#define NE    64
#define TOPK  9

#define ROWS     32            // rows per block
#define DC       64            // k-elements per chunk
#define NCHUNK   (DIM / DC)    // 32
#define HALF     (NCHUNK / 2)  // 16 chunks per K-half
#define NTHREADS 512           // 8 waves: (kh, wv) = (w>>2, w&3)
#define NBUF     4             // x-stage ring depth per K-half

typedef short  short8  __attribute__((ext_vector_type(8)));
typedef float  float4_ __attribute__((ext_vector_type(4)));
typedef unsigned short ushort_t;

__device__ __forceinline__ void async16(const void* g, void* l) {
    __builtin_amdgcn_global_load_lds(
        (const __attribute__((address_space(1))) void*)g,
        (__attribute__((address_space(3))) void*)l, 16, 0, 0);
}

__device__ __forceinline__ unsigned pk2(float a, float b) {
    float2 f; f.x = a; f.y = b;
    __hip_bfloat162 h = __float22bfloat162_rn(f);   // low16 = bf16(a)
    unsigned u;
    __builtin_memcpy(&u, &h, 4);
    return u;
}

// 8 fp32 -> bf16 hi frag + bf16 lo frag (2-term split)
__device__ __forceinline__ void cvt8(const float4_ va, const float4_ vb,
                                     short8* h, short8* l) {
    union { short8 s; unsigned u[4]; } H, L;
    const float f[8] = {va[0], va[1], va[2], va[3], vb[0], vb[1], vb[2], vb[3]};
#pragma unroll
    for (int i = 0; i < 4; ++i) {
        const float a = f[2 * i], b = f[2 * i + 1];
        const unsigned p = pk2(a, b);
        H.u[i] = p;
        const float ha = __uint_as_float(p << 16);
        const float hb = __uint_as_float(p & 0xffff0000u);
        L.u[i] = pk2(a - ha, b - hb);
    }
    *h = H.s; *l = L.s;
}

__device__ __forceinline__ void wave_max64_2(float& a, float& b) {
#pragma unroll
    for (int off = 32; off > 0; off >>= 1) {
        const float ax = __shfl_xor(a, off, 64);
        const float bx = __shfl_xor(b, off, 64);
        a = fmaxf(a, ax);
        b = fmaxf(b, bx);
    }
}

__device__ __forceinline__ void wave_sum64_3(float& a, float& b, float& c) {
#pragma unroll
    for (int off = 32; off > 0; off >>= 1) {
        const float ax = __shfl_xor(a, off, 64);
        const float bx = __shfl_xor(b, off, 64);
        const float cx = __shfl_xor(c, off, 64);
        a += ax;
        b += bx;
        c += cx;
    }
}

// ---- prep: Wr|Wn (fp32, D x 64 each) -> B-fragment-ordered bf16 hi/lo ----
// slot s=(kcg*8+ct)*2+t holds 512 bf16: elem l*8+j = B[k=kcg*32+(l>>4)*8+j][n=ct*16+(l&15)]
__global__ __launch_bounds__(256)
void prep_w(const float* __restrict__ Wr, const float* __restrict__ Wn,
            ushort_t* __restrict__ wsW)
{
    const int gid = blockIdx.x * 256 + threadIdx.x;   // [0, 64*8*64)
    const int l   = gid & 63;
    const int ct  = (gid >> 6) & 7;
    const int kcg = gid >> 9;                         // 0..63
    const int n   = ct * 16 + (l & 15);
    const int k0  = kcg * 32 + (l >> 4) * 8;
    const float* src = (n < NE) ? (Wr + n) : (Wn + (n - NE));
    union { short8 s; ushort_t us[8]; } H, L;
#pragma unroll
    for (int j = 0; j < 8; ++j) {
        const float v = src[(size_t)(k0 + j) * NE];
        const unsigned uv = __float_as_uint(v);
        const unsigned hb = (uv + 0x7fffu + ((uv >> 16) & 1u)) & 0xffff0000u;
        const float lo = v - __uint_as_float(hb);
        const unsigned ul = __float_as_uint(lo);
        H.us[j] = (ushort_t)(hb >> 16);
        L.us[j] = (ushort_t)((ul + 0x7fffu + ((ul >> 16) & 1u)) >> 16);
    }
    const size_t s0 = (size_t)(kcg * 8 + ct) * 2;     // slot pair index
    *(short8*)(wsW + s0 * 512 + l * 8)         = H.s;
    *(short8*)(wsW + (s0 + 1) * 512 + l * 8)   = L.s;
}

// B fragments for one chunk, double-buffered in registers across chunks.
struct BFrag { short8 h[2][2]; short8 l[2][2]; };

__device__ __forceinline__ void load_b(const char* __restrict__ wsB,
                                       int ch, int cg, int lane, BFrag& b) {
#pragma unroll
    for (int kc = 0; kc < 2; ++kc)
#pragma unroll
        for (int cc = 0; cc < 2; ++cc) {
            const size_t off = (size_t)(((ch * 2 + kc) * 8) + 2 * cg + cc) * 2048
                             + (size_t)lane * 16;
            b.h[kc][cc] = *(const short8*)(wsB + off);
            b.l[kc][cc] = *(const short8*)(wsB + off + 1024);
        }
}

__device__ __forceinline__ void mfma_chunk(const float* __restrict__ xb,
                                           const int (&aoff)[2][2],
                                           const BFrag& b,
                                           float4_ (&acc)[2][2]) {
#pragma unroll
    for (int kc = 0; kc < 2; ++kc)
#pragma unroll
        for (int rt = 0; rt < 2; ++rt) {
            const float4_ va = *(const float4_*)(xb + rt * 1024 + aoff[kc][0]);
            const float4_ vb = *(const float4_*)(xb + rt * 1024 + aoff[kc][1]);
            short8 ah, al;
            cvt8(va, vb, &ah, &al);
#pragma unroll
            for (int cc = 0; cc < 2; ++cc) {
                acc[rt][cc] = __builtin_amdgcn_mfma_f32_16x16x32_bf16(ah, b.h[kc][cc], acc[rt][cc], 0, 0, 0);
                acc[rt][cc] = __builtin_amdgcn_mfma_f32_16x16x32_bf16(al, b.h[kc][cc], acc[rt][cc], 0, 0, 0);
                acc[rt][cc] = __builtin_amdgcn_mfma_f32_16x16x32_bf16(ah, b.l[kc][cc], acc[rt][cc], 0, 0, 0);
            }
        }
}

__global__ __launch_bounds__(NTHREADS, 4)
void moe_main(const float* __restrict__ x,
              const float* __restrict__ br,
              const float* __restrict__ bn,
              const float* __restrict__ noise_eps,
              const float* __restrict__ gumbel,
              const ushort_t* __restrict__ wsW,
              float* __restrict__ out)
{
    // x stage: 2 K-half rings x NBUF x 2048 floats = 64 KB; epilogue reuses it
    __shared__ __align__(16) float smem[2 * NBUF * 2048];

    const int t    = threadIdx.x;
    const int lane = t & 63;
    const int w    = t >> 6;          // wave 0..7
    const int kh   = w >> 2;          // K-half: chunks [kh*16, kh*16+16)
    const int wv   = w & 3;           // col group -> col-tiles {2wv, 2wv+1}
    const int c4   = lane & 15;
    const int q    = lane >> 4;
    const int row0 = blockIdx.x * ROWS;
    const int XB   = kh * (NBUF * 2048);   // this half's ring base (floats)

    // x staging (per K-half group of 4 waves): 8 issues/chunk; wave wv does
    // i=2wv,2wv+1; issue i covers rows 4i..4i+3; lane l -> row 4i+(l>>4);
    // LDS granule pos p=l&15 holds global granule gk=p^(row&15)
    const float* gxb[2];
    int lxo[2];
#pragma unroll
    for (int ii = 0; ii < 2; ++ii) {
        const int i  = 2 * wv + ii;
        const int r  = 4 * i + q;
        const int gk = c4 ^ (r & 15);
        gxb[ii] = x + (size_t)(row0 + r) * DIM + kh * (HALF * DC) + gk * 4;
        lxo[ii] = i * 256;            // float offset within a stage buffer
    }

    // A-read offsets (chunk-invariant): row m=rt*16+c4, granules (kc*8+q*2)^c4, +1^c4
    int aoff[2][2];
#pragma unroll
    for (int kc = 0; kc < 2; ++kc) {
        const int g0 = kc * 8 + q * 2;
        aoff[kc][0] = c4 * 64 + ((g0 ^ c4) * 4);
        aoff[kc][1] = c4 * 64 + (((g0 + 1) ^ c4) * 4);
    }

    float4_ acc[2][2];
#pragma unroll
    for (int rt = 0; rt < 2; ++rt)
#pragma unroll
        for (int cc = 0; cc < 2; ++cc)
            acc[rt][cc] = (float4_)(0.f);

    const char* wsB = (const char*)wsW;
    const int chb = kh * HALF;        // global chunk base for this half

    // ---- prologue: stage local chunks 0..2 (depth 3), B(0) into regs ----
#pragma unroll
    for (int p = 0; p < NBUF - 1; ++p)
#pragma unroll
        for (int ii = 0; ii < 2; ++ii)
            async16(gxb[ii] + p * DC, &smem[XB + p * 2048 + lxo[ii]]);

    BFrag bA, bB;
    load_b(wsB, chb, wv, lane, bA);

    // Main loop over local chunks i (16 per wave), unrolled x2 for B reg dbuf.
    // Top-of-step outstanding (steady): S(i):2 S(i+1):2 B(i):8 S(i+2):2 = 14
    // -> vmcnt(12) retires exactly S(i). Tail steps use exact counts.
#pragma unroll 1
    for (int i = 0; i < HALF - 4; i += 2) {
        // ---- even step: use bA, prefetch bB ----
        asm volatile("s_waitcnt vmcnt(12)" ::: "memory");
        __builtin_amdgcn_s_barrier();
        asm volatile("" ::: "memory");
        load_b(wsB, chb + i + 1, wv, lane, bB);
#pragma unroll
        for (int ii = 0; ii < 2; ++ii)
            async16(gxb[ii] + (i + 3) * DC, &smem[XB + ((i + 3) & 3) * 2048 + lxo[ii]]);
        __builtin_amdgcn_sched_barrier(0);   // pin load-issues above compute
        mfma_chunk(&smem[XB + (i & 3) * 2048], aoff, bA, acc);

        // ---- odd step: use bB, prefetch bA ----
        asm volatile("s_waitcnt vmcnt(12)" ::: "memory");
        __builtin_amdgcn_s_barrier();
        asm volatile("" ::: "memory");
        load_b(wsB, chb + i + 2, wv, lane, bA);
#pragma unroll
        for (int ii = 0; ii < 2; ++ii)
            async16(gxb[ii] + (i + 4) * DC, &smem[XB + ((i + 4) & 3) * 2048 + lxo[ii]]);
        __builtin_amdgcn_sched_barrier(0);
        mfma_chunk(&smem[XB + ((i + 1) & 3) * 2048], aoff, bB, acc);
    }

    // ---- tail: steps 12..15, exact counted waits ----
    // step 12: outstanding S12 S13 B12 S14 = 14
    asm volatile("s_waitcnt vmcnt(12)" ::: "memory");
    __builtin_amdgcn_s_barrier();
    asm volatile("" ::: "memory");
    load_b(wsB, chb + 13, wv, lane, bB);
#pragma unroll
    for (int ii = 0; ii < 2; ++ii)
        async16(gxb[ii] + 15 * DC, &smem[XB + 3 * 2048 + lxo[ii]]);
    __builtin_amdgcn_sched_barrier(0);
    mfma_chunk(&smem[XB + 0 * 2048], aoff, bA, acc);

    // step 13: outstanding S13 S14 B13 S15 = 14
    asm volatile("s_waitcnt vmcnt(12)" ::: "memory");
    __builtin_amdgcn_s_barrier();
    asm volatile("" ::: "memory");
    load_b(wsB, chb + 14, wv, lane, bA);
    __builtin_amdgcn_sched_barrier(0);
    mfma_chunk(&smem[XB + 1 * 2048], aoff, bB, acc);

    // step 14: outstanding S14 S15 B14 = 12 -> vmcnt(10) retires S14
    asm volatile("s_waitcnt vmcnt(10)" ::: "memory");
    __builtin_amdgcn_s_barrier();
    asm volatile("" ::: "memory");
    load_b(wsB, chb + 15, wv, lane, bB);
    __builtin_amdgcn_sched_barrier(0);
    mfma_chunk(&smem[XB + 2 * 2048], aoff, bA, acc);

    // step 15: outstanding S15 B15 = 10 -> vmcnt(8) retires S15
    asm volatile("s_waitcnt vmcnt(8)" ::: "memory");
    __builtin_amdgcn_s_barrier();
    asm volatile("" ::: "memory");
    __builtin_amdgcn_sched_barrier(0);
    mfma_chunk(&smem[XB + 3 * 2048], aoff, bB, acc);

    // ---- epilogue: transpose K-half partials through LDS, merge, wave ops ----
    __syncthreads();                   // drain everything; safe to reuse LDS
    // layout: R0[0..2079] N0[2080..4159] R1[4160..6239] N1[6240..8319] (32x65 each)
    {
        float* base = &smem[kh * 4160];
#pragma unroll
        for (int rt = 0; rt < 2; ++rt)
#pragma unroll
            for (int cc = 0; cc < 2; ++cc) {
                const int colg = (2 * wv + cc) * 16 + c4;  // 0..127
                float* bp = (colg < NE) ? base : (base + 2080);
                const int col = colg & 63;
#pragma unroll
                for (int v = 0; v < 4; ++v) {
                    const int row = rt * 16 + q * 4 + v;   // C/D: col=lane&15, row=quad*4+reg
                    bp[row * 65 + col] = acc[rt][cc][v];
                }
            }
    }
    __syncthreads();

    const float br_l = br[lane];
    const float bn_l = bn[lane];

    // prefetch per-row randomness (4 rows per wave)
    float epsv[4], gumv[4];
#pragma unroll
    for (int r = 0; r < 4; ++r) {
        const int row = row0 + w * 4 + r;
        epsv[r] = noise_eps[(size_t)row * NE + lane];
        gumv[r] = gumbel  [(size_t)row * NE + lane];
    }

    float imp_acc = 0.f, load_acc = 0.f;
    float* out_em   = out;
    float* out_rp   = out + (size_t)N_TOK * NE;
    float* out_imp  = out + (size_t)2 * N_TOK * NE;
    float* out_load = out_imp + NE;

#pragma unroll 1
    for (int r = 0; r < 4; ++r) {
        const int lrow = w * 4 + r;
        const int row  = row0 + lrow;
        const float raw = smem[lrow * 65 + lane] + smem[4160 + lrow * 65 + lane] + br_l;
        const float nl  = smem[2080 + lrow * 65 + lane] + smem[6240 + lrow * 65 + lane] + bn_l;
        const float sd = fmaxf(nl, 0.f) + log1pf(expf(-fabsf(nl))) + 0.01f;
        const float noisy = fmaf(epsv[r], sd, raw);

        // ---- threshold = 9th largest via ballot binary search (bit-exact) ----
        const unsigned uk  = __float_as_uint(noisy);
        const unsigned key = uk ^ ((uk & 0x80000000u) ? 0xFFFFFFFFu : 0x80000000u);
        unsigned res = 0;
#pragma unroll
        for (int bit = 31; bit >= 0; --bit) {
            const unsigned cand = res | (1u << bit);
            const int cnt = __popcll(__ballot(key >= cand));
            if (cnt >= TOPK) res = cand;
        }
        const float thr  = __uint_as_float(res ^ ((res & 0x80000000u) ? 0x80000000u : 0xFFFFFFFFu));
        const float hard = (key >= res) ? 1.f : 0.f;

        // fused reductions: one dual-max chain, one triple-sum chain
        const float g = noisy + gumv[r];
        float mg = g, mr = raw;
        wave_max64_2(mg, mr);

        const float eg = expf(g - mg);
        const float en = expf(noisy - thr);   // softmax shift-invariant
        const float er = expf(raw - mr);
        float sg = eg, sn = en, sr = er;
        wave_sum64_3(sg, sn, sr);

        const float ms = eg / sg;
        const float em = (hard - ms) + ms;
        const float rp = en / sn;
        imp_acc += er / sr;

        const float z = (thr - raw) / sd;
        load_acc += 0.5f * erfcf(z * 45.254833995939045f);

        out_em[(size_t)row * NE + lane] = em;
        out_rp[(size_t)row * NE + lane] = rp;
    }

    __syncthreads();                   // LDS reads done; reuse for reduction
    smem[w * 64 + lane]       = imp_acc;
    smem[512 + w * 64 + lane] = load_acc;
    __syncthreads();
    if (w == 0) {
        float s1 = 0.f, s2 = 0.f;
#pragma unroll
        for (int i = 0; i < 8; ++i) {
            s1 += smem[i * 64 + lane];
            s2 += smem[512 + i * 64 + lane];
        }
        atomicAdd(&out_imp[lane], s1);
        atomicAdd(&out_load[lane], s2);
    }
}

extern "C" void kernel_launch(void* const* d_in, const int* in_sizes, int n_in,
                              void* d_out, int out_size, void* d_ws, size_t ws_size,
                              hipStream_t stream)
{
    const float* x         = (const float*)d_in[0];
    const float* Wr        = (const float*)d_in[1];
    const float* br        = (const float*)d_in[2];
    const float* Wn        = (const float*)d_in[3];
    const float* bn        = (const float*)d_in[4];
    const float* noise_eps = (const float*)d_in[5];
    const float* gumbel    = (const float*)d_in[6];
    float* out = (float*)d_out;
    ushort_t* wsW = (ushort_t*)d_ws;   // 1 MB (64*8*2 slots x 1 KB)

    (void)hipMemsetAsync((char*)d_out + (size_t)2 * N_TOK * NE * sizeof(float), 0,
                         2 * NE * sizeof(float), stream);
    prep_w<<<128, 256, 0, stream>>>(Wr, Wn, wsW);
    moe_main<<<N_TOK / ROWS, NTHREADS, 0, stream>>>(
        x, br, bn, noise_eps, gumbel, wsW, out);
}